// Round 1
// baseline (801.620 us; speedup 1.0000x reference)
//
#include <hip/hip_runtime.h>
#include <math.h>

#define H_DIM 1024
#define W_DIM 1536
#define HW_PIX (H_DIM * W_DIM)          // 1572864 pixels per (batch,channel)
#define NBATCH 8
#define QPB (HW_PIX / 4)                // quads per batch = 393216
#define BLOCKS_PER_BATCH (QPB / 256)    // 1536
#define RESOLUTION 1024
#define TC_LEN 256

struct Sliders {
    const float* temperature; const float* tint; const float* exposure; const float* contrast;
    const float* highlights;  const float* shadows; const float* whites; const float* blacks;
    const float* vibrance;    const float* saturation;
};

__device__ __forceinline__ float denorm(float v, float lo, float hi) {
    return lo + 0.5f * (v + 1.0f) * (hi - lo);
}
__device__ __forceinline__ float clampf(float x, float lo, float hi) {
    return fminf(fmaxf(x, lo), hi);
}
__device__ __forceinline__ float sigmoidf(float x) {
    return 1.0f / (1.0f + __expf(-x));
}

struct FrontP { float sr, sg, sb, em, cf; };

__device__ __forceinline__ FrontP front_params(const Sliders& S, int b) {
    float temp = clampf(denorm(S.temperature[b], 2000.f, 50000.f), 2000.f, 50000.f);
    float tr   = 6500.f / temp;
    float red  = sqrtf(tr);
    float blue = 1.0f / sqrtf(tr);
    float ts   = clampf(denorm(S.tint[b], -150.f, 150.f) * (1.0f / 150.0f), -1.5f, 1.5f);
    float green = 1.0f - 0.1f * ts;
    red  *= (1.0f + 0.05f * ts);
    blue *= (1.0f - 0.05f * ts);
    float norm = fmaxf(fmaxf(red, green), blue);
    float inv  = 1.0f / fmaxf(norm, 1e-4f);
    FrontP p;
    p.sr = red * inv; p.sg = green * inv; p.sb = blue * inv;
    p.em = exp2f(denorm(S.exposure[b], -5.f, 5.f));
    p.cf = 1.0f + denorm(S.contrast[b], -100.f, 100.f) * 0.01f;
    return p;
}

// WB (pre-folded scale incl. norm) -> clip[0,4] -> exposure -> clip[0,4] -> contrast -> clip[0,1]
__device__ __forceinline__ float front_chan(float x, float s, float em, float cf) {
    x = clampf(x, 0.f, 1.f);
    x = clampf(x * s, 0.f, 4.f);
    x = clampf(x * em, 0.f, 4.f);
    return clampf((x - 0.5f) * cf + 0.5f, 0.f, 1.f);
}

__device__ __forceinline__ float luminance(float r, float g, float b) {
    return 0.2126f * r + 0.7152f * g + 0.0722f * b;
}

// Block (256 threads = 4 waves) sum; result valid on thread 0 only.
__device__ __forceinline__ float block_sum(float v) {
    #pragma unroll
    for (int o = 32; o > 0; o >>= 1) v += __shfl_down(v, o, 64);
    __shared__ float s[4];
    int lane = threadIdx.x & 63, wid = threadIdx.x >> 6;
    if (lane == 0) s[wid] = v;
    __syncthreads();
    float r = 0.f;
    if (threadIdx.x == 0) r = s[0] + s[1] + s[2] + s[3];
    return r;
}

// R = region index whose sigmoid-sum we reduce (0..3). Regions 0..R-1 are replayed
// elementwise on luma using the already-finalized means in ws_sums.
template <int R, bool USE_LUMA>
__global__ __launch_bounds__(256)
void reduce_kernel(const float* __restrict__ image, Sliders S,
                   float* __restrict__ ws_luma, float* __restrict__ ws_sums) {
    const int b   = blockIdx.x / BLOCKS_PER_BATCH;
    const int q   = (blockIdx.x % BLOCKS_PER_BATCH) * 256 + threadIdx.x;
    const int off = q * 4;

    const float pivots[4] = {0.7f, 0.3f, 0.9f, 0.1f};
    const float invw[4]   = {1.0f / 0.1f, 1.0f / 0.12f, 1.0f / 0.08f, 1.0f / 0.08f};
    const float* sliders[4] = {S.highlights, S.shadows, S.whites, S.blacks};

    float strength[4], meanv[4];
    #pragma unroll
    for (int k = 0; k < R; k++) {
        strength[k] = denorm(sliders[k][b], -100.f, 100.f) * 0.01f;
        meanv[k]    = ws_sums[b * 4 + k] * (1.0f / (float)HW_PIX);
    }

    float4 L;
    if (USE_LUMA && R > 0) {
        L = *reinterpret_cast<const float4*>(ws_luma + (size_t)b * HW_PIX + off);
    } else {
        FrontP p = front_params(S, b);
        const float* base = image + (size_t)b * 3 * HW_PIX + off;
        float4 r4 = *reinterpret_cast<const float4*>(base);
        float4 g4 = *reinterpret_cast<const float4*>(base + HW_PIX);
        float4 b4 = *reinterpret_cast<const float4*>(base + 2 * HW_PIX);
        float* rr = reinterpret_cast<float*>(&r4);
        float* gg = reinterpret_cast<float*>(&g4);
        float* bb = reinterpret_cast<float*>(&b4);
        float* ll = reinterpret_cast<float*>(&L);
        #pragma unroll
        for (int i = 0; i < 4; i++) {
            float r = front_chan(rr[i], p.sr, p.em, p.cf);
            float g = front_chan(gg[i], p.sg, p.em, p.cf);
            float bl = front_chan(bb[i], p.sb, p.em, p.cf);
            ll[i] = clampf(luminance(r, g, bl), 0.f, 1.f);
        }
        if (USE_LUMA && R == 0)
            *reinterpret_cast<float4*>(ws_luma + (size_t)b * HW_PIX + off) = L;
    }

    float sum = 0.f;
    const float* ll = reinterpret_cast<const float*>(&L);
    #pragma unroll
    for (int i = 0; i < 4; i++) {
        float lum = ll[i];
        #pragma unroll
        for (int k = 0; k < R; k++) {
            float mask = sigmoidf((lum - pivots[k]) * invw[k]);
            lum = clampf(lum + strength[k] * (mask - meanv[k]), 0.f, 1.f);
        }
        sum += sigmoidf((lum - pivots[R]) * invw[R]);
    }
    sum = block_sum(sum);
    if (threadIdx.x == 0) atomicAdd(&ws_sums[b * 4 + R], sum);
}

__global__ __launch_bounds__(256)
void final_kernel(const float* __restrict__ image, const float* __restrict__ tone_curve,
                  Sliders S, const float* __restrict__ ws_sums, float* __restrict__ out) {
    const int b = blockIdx.x / BLOCKS_PER_BATCH;

    // Build this batch's RESOLUTION-entry curve in LDS (replicates the reference's
    // align_corners interp of 256 control points -> 1024 samples).
    __shared__ float curve[RESOLUTION];
    const float* tc = tone_curve + b * TC_LEN;
    for (int j = threadIdx.x; j < RESOLUTION; j += 256) {
        float src = (float)j * ((float)(TC_LEN - 1) / (float)(RESOLUTION - 1));
        float fi  = floorf(src);
        int   i0  = (int)fi;
        int   i1  = min(i0 + 1, TC_LEN - 1);
        float w   = src - fi;
        curve[j]  = tc[i0] * (1.0f - w) + tc[i1] * w;
    }
    __syncthreads();

    const int q   = (blockIdx.x % BLOCKS_PER_BATCH) * 256 + threadIdx.x;
    const int off = q * 4;

    const float pivots[4] = {0.7f, 0.3f, 0.9f, 0.1f};
    const float invw[4]   = {1.0f / 0.1f, 1.0f / 0.12f, 1.0f / 0.08f, 1.0f / 0.08f};
    const float* sliders[4] = {S.highlights, S.shadows, S.whites, S.blacks};

    FrontP p = front_params(S, b);
    float strength[4], meanv[4];
    #pragma unroll
    for (int k = 0; k < 4; k++) {
        strength[k] = denorm(sliders[k][b], -100.f, 100.f) * 0.01f;
        meanv[k]    = ws_sums[b * 4 + k] * (1.0f / (float)HW_PIX);
    }
    float vib  = denorm(S.vibrance[b],   -100.f, 100.f) * 0.01f;
    float satg = 1.0f + denorm(S.saturation[b], -100.f, 100.f) * 0.01f;

    const float* base = image + (size_t)b * 3 * HW_PIX + off;
    float4 r4 = *reinterpret_cast<const float4*>(base);
    float4 g4 = *reinterpret_cast<const float4*>(base + HW_PIX);
    float4 b4 = *reinterpret_cast<const float4*>(base + 2 * HW_PIX);
    float* rr = reinterpret_cast<float*>(&r4);
    float* gg = reinterpret_cast<float*>(&g4);
    float* bb = reinterpret_cast<float*>(&b4);

    #pragma unroll
    for (int i = 0; i < 4; i++) {
        float r  = front_chan(rr[i], p.sr, p.em, p.cf);
        float g  = front_chan(gg[i], p.sg, p.em, p.cf);
        float bl = front_chan(bb[i], p.sb, p.em, p.cf);
        float lum = clampf(luminance(r, g, bl), 0.f, 1.f);

        // 4 sequential regions
        #pragma unroll
        for (int k = 0; k < 4; k++) {
            float mask = sigmoidf((lum - pivots[k]) * invw[k]);
            float nl   = clampf(lum + strength[k] * (mask - meanv[k]), 0.f, 1.f);
            float ratio = (lum > 1e-4f) ? nl / fmaxf(lum, 1e-4f) : 1.0f;
            r  = clampf(r * ratio, 0.f, 1.f);
            g  = clampf(g * ratio, 0.f, 1.f);
            bl = clampf(bl * ratio, 0.f, 1.f);
            lum = nl;
        }

        // tone curve (luma recomputed from img per reference)
        float tl = clampf(luminance(r, g, bl), 0.f, 1.f);
        float coords = tl * (float)(RESOLUTION - 1);
        float fidx = floorf(coords);
        int   i0 = (int)fidx;
        int   i1 = min(i0 + 1, RESOLUTION - 1);
        float w  = coords - fidx;
        float target = (1.0f - w) * curve[i0] + w * curve[i1];
        float ratio  = (tl > 1e-5f) ? target / fmaxf(tl, 1e-5f) : 1.0f;
        r  = clampf(r * ratio, 0.f, 1.f);
        g  = clampf(g * ratio, 0.f, 1.f);
        bl = clampf(bl * ratio, 0.f, 1.f);

        // vibrance
        float l2 = luminance(r, g, bl);
        float cr = r - l2, cg = g - l2, cb = bl - l2;
        float cn = sqrtf(cr * cr + cg * cg + cb * cb + 1e-6f);
        float gmask = __expf(-4.0f * cn);
        float vg = clampf(1.0f + vib * gmask, 0.2f, 4.0f);
        r  = clampf(l2 + cr * vg, 0.f, 1.f);
        g  = clampf(l2 + cg * vg, 0.f, 1.f);
        bl = clampf(l2 + cb * vg, 0.f, 1.f);

        // saturation (final clip(0,1) is identical to the saturation clip)
        float l3 = luminance(r, g, bl);
        r  = clampf(l3 + (r - l3) * satg, 0.f, 1.f);
        g  = clampf(l3 + (g - l3) * satg, 0.f, 1.f);
        bl = clampf(l3 + (bl - l3) * satg, 0.f, 1.f);

        rr[i] = r; gg[i] = g; bb[i] = bl;
    }

    float* obase = out + (size_t)b * 3 * HW_PIX + off;
    *reinterpret_cast<float4*>(obase)              = r4;
    *reinterpret_cast<float4*>(obase + HW_PIX)     = g4;
    *reinterpret_cast<float4*>(obase + 2 * HW_PIX) = b4;
}

extern "C" void kernel_launch(void* const* d_in, const int* in_sizes, int n_in,
                              void* d_out, int out_size, void* d_ws, size_t ws_size,
                              hipStream_t stream) {
    const float* image      = (const float*)d_in[0];
    const float* tone_curve = (const float*)d_in[1];
    Sliders S;
    S.temperature = (const float*)d_in[2];
    S.tint        = (const float*)d_in[3];
    S.exposure    = (const float*)d_in[4];
    S.contrast    = (const float*)d_in[5];
    S.highlights  = (const float*)d_in[6];
    S.shadows     = (const float*)d_in[7];
    S.whites      = (const float*)d_in[8];
    S.blacks      = (const float*)d_in[9];
    S.vibrance    = (const float*)d_in[10];
    S.saturation  = (const float*)d_in[11];
    float* out = (float*)d_out;

    float* ws_sums = (float*)d_ws;                 // 32 floats (B x 4 region sums)
    float* ws_luma = (float*)d_ws + 64;            // 256-byte offset, 50 MB luma cache
    bool use_luma = ws_size >= 256 + (size_t)NBATCH * HW_PIX * sizeof(float);

    hipMemsetAsync(ws_sums, 0, 256, stream);       // zero the atomic accumulators

    dim3 grid(NBATCH * BLOCKS_PER_BATCH), block(256);
    if (use_luma) {
        reduce_kernel<0, true><<<grid, block, 0, stream>>>(image, S, ws_luma, ws_sums);
        reduce_kernel<1, true><<<grid, block, 0, stream>>>(image, S, ws_luma, ws_sums);
        reduce_kernel<2, true><<<grid, block, 0, stream>>>(image, S, ws_luma, ws_sums);
        reduce_kernel<3, true><<<grid, block, 0, stream>>>(image, S, ws_luma, ws_sums);
    } else {
        reduce_kernel<0, false><<<grid, block, 0, stream>>>(image, S, ws_luma, ws_sums);
        reduce_kernel<1, false><<<grid, block, 0, stream>>>(image, S, ws_luma, ws_sums);
        reduce_kernel<2, false><<<grid, block, 0, stream>>>(image, S, ws_luma, ws_sums);
        reduce_kernel<3, false><<<grid, block, 0, stream>>>(image, S, ws_luma, ws_sums);
    }
    final_kernel<<<grid, block, 0, stream>>>(image, tone_curve, S, ws_sums, out);
}

// Round 2
// 461.513 us; speedup vs baseline: 1.7369x; 1.7369x over previous
//
#include <hip/hip_runtime.h>
#include <math.h>

#define H_DIM 1024
#define W_DIM 1536
#define HW_PIX (H_DIM * W_DIM)          // 1572864 pixels per (batch,channel)
#define NBATCH 8
#define QPB (HW_PIX / 4)                // quads per batch = 393216
#define BPB 192                          // reduce blocks per batch
#define QPT (QPB / (BPB * 256))          // quads per thread in reduce = 8
#define FBPB (QPB / 256)                 // final blocks per batch = 1536
#define RESOLUTION 1024
#define TC_LEN 256

struct Sliders {
    const float* temperature; const float* tint; const float* exposure; const float* contrast;
    const float* highlights;  const float* shadows; const float* whites; const float* blacks;
    const float* vibrance;    const float* saturation;
};

__device__ __forceinline__ float denorm(float v, float lo, float hi) {
    return lo + 0.5f * (v + 1.0f) * (hi - lo);
}
__device__ __forceinline__ float clampf(float x, float lo, float hi) {
    return fminf(fmaxf(x, lo), hi);
}
__device__ __forceinline__ float sigmoidf(float x) {
    return 1.0f / (1.0f + __expf(-x));
}

struct FrontP { float sr, sg, sb, em, cf; };

__device__ __forceinline__ FrontP front_params(const Sliders& S, int b) {
    float temp = clampf(denorm(S.temperature[b], 2000.f, 50000.f), 2000.f, 50000.f);
    float tr   = 6500.f / temp;
    float red  = sqrtf(tr);
    float blue = 1.0f / sqrtf(tr);
    float ts   = clampf(denorm(S.tint[b], -150.f, 150.f) * (1.0f / 150.0f), -1.5f, 1.5f);
    float green = 1.0f - 0.1f * ts;
    red  *= (1.0f + 0.05f * ts);
    blue *= (1.0f - 0.05f * ts);
    float norm = fmaxf(fmaxf(red, green), blue);
    float inv  = 1.0f / fmaxf(norm, 1e-4f);
    FrontP p;
    p.sr = red * inv; p.sg = green * inv; p.sb = blue * inv;
    p.em = exp2f(denorm(S.exposure[b], -5.f, 5.f));
    p.cf = 1.0f + denorm(S.contrast[b], -100.f, 100.f) * 0.01f;
    return p;
}

__device__ __forceinline__ float front_chan(float x, float s, float em, float cf) {
    x = clampf(x, 0.f, 1.f);
    x = clampf(x * s, 0.f, 4.f);
    x = clampf(x * em, 0.f, 4.f);
    return clampf((x - 0.5f) * cf + 0.5f, 0.f, 1.f);
}

__device__ __forceinline__ float luminance(float r, float g, float b) {
    return 0.2126f * r + 0.7152f * g + 0.0722f * b;
}

// Block (256 threads = 4 waves) sum; result valid on thread 0 only.
__device__ __forceinline__ float block_sum(float v) {
    #pragma unroll
    for (int o = 32; o > 0; o >>= 1) v += __shfl_down(v, o, 64);
    __shared__ float s[4];
    int lane = threadIdx.x & 63, wid = threadIdx.x >> 6;
    if (lane == 0) s[wid] = v;
    __syncthreads();
    float r = 0.f;
    if (threadIdx.x == 0) r = s[0] + s[1] + s[2] + s[3];
    return r;
}

// Sum previous kernel's per-block partials with block-uniform (scalar) loads.
__device__ __forceinline__ float partial_mean(const float* __restrict__ ws_part, int k, int b) {
    const float* pp = ws_part + (k * NBATCH + b) * BPB;
    float s = 0.f;
    for (int j = 0; j < BPB; j++) s += pp[j];
    return s * (1.0f / (float)HW_PIX);
}

// R = region whose sigmoid-sum we reduce (0..3). Regions 0..R-1 replayed elementwise
// on luma using means reconstructed from earlier kernels' per-block partials.
// No atomics: each block writes its partial to a unique slot.
template <int R, bool USE_LUMA>
__global__ __launch_bounds__(256)
void reduce_kernel(const float* __restrict__ image, Sliders S,
                   float* __restrict__ ws_luma, float* __restrict__ ws_part) {
    const int b   = blockIdx.x / BPB;
    const int blk = blockIdx.x % BPB;

    const float pivots[4] = {0.7f, 0.3f, 0.9f, 0.1f};
    const float invw[4]   = {1.0f / 0.1f, 1.0f / 0.12f, 1.0f / 0.08f, 1.0f / 0.08f};
    const float* sliders[4] = {S.highlights, S.shadows, S.whites, S.blacks};

    float strength[4], meanv[4];
    #pragma unroll
    for (int k = 0; k < R; k++) {
        strength[k] = denorm(sliders[k][b], -100.f, 100.f) * 0.01f;
        meanv[k]    = partial_mean(ws_part, k, b);
    }
    FrontP p = front_params(S, b);

    float sum = 0.f;
    #pragma unroll
    for (int it = 0; it < QPT; it++) {
        const int q   = blk * (256 * QPT) + it * 256 + threadIdx.x;
        const int off = q * 4;

        float4 L;
        if (USE_LUMA && R > 0) {
            L = *reinterpret_cast<const float4*>(ws_luma + (size_t)b * HW_PIX + off);
        } else {
            const float* base = image + (size_t)b * 3 * HW_PIX + off;
            float4 r4 = *reinterpret_cast<const float4*>(base);
            float4 g4 = *reinterpret_cast<const float4*>(base + HW_PIX);
            float4 b4 = *reinterpret_cast<const float4*>(base + 2 * HW_PIX);
            float* rr = reinterpret_cast<float*>(&r4);
            float* gg = reinterpret_cast<float*>(&g4);
            float* bb = reinterpret_cast<float*>(&b4);
            float* ll = reinterpret_cast<float*>(&L);
            #pragma unroll
            for (int i = 0; i < 4; i++) {
                float r  = front_chan(rr[i], p.sr, p.em, p.cf);
                float g  = front_chan(gg[i], p.sg, p.em, p.cf);
                float bl = front_chan(bb[i], p.sb, p.em, p.cf);
                ll[i] = clampf(luminance(r, g, bl), 0.f, 1.f);
            }
            if (USE_LUMA && R == 0)
                *reinterpret_cast<float4*>(ws_luma + (size_t)b * HW_PIX + off) = L;
        }

        const float* ll = reinterpret_cast<const float*>(&L);
        #pragma unroll
        for (int i = 0; i < 4; i++) {
            float lum = ll[i];
            #pragma unroll
            for (int k = 0; k < R; k++) {
                float mask = sigmoidf((lum - pivots[k]) * invw[k]);
                lum = clampf(lum + strength[k] * (mask - meanv[k]), 0.f, 1.f);
            }
            sum += sigmoidf((lum - pivots[R]) * invw[R]);
        }
    }
    sum = block_sum(sum);
    if (threadIdx.x == 0) ws_part[(R * NBATCH + b) * BPB + blk] = sum;
}

__global__ __launch_bounds__(256)
void final_kernel(const float* __restrict__ image, const float* __restrict__ tone_curve,
                  Sliders S, const float* __restrict__ ws_part, float* __restrict__ out) {
    const int b = blockIdx.x / FBPB;

    // Build this batch's RESOLUTION-entry curve in LDS (replicates the reference's
    // align_corners interp of 256 control points -> 1024 samples).
    __shared__ float curve[RESOLUTION];
    const float* tc = tone_curve + b * TC_LEN;
    for (int j = threadIdx.x; j < RESOLUTION; j += 256) {
        float src = (float)j * ((float)(TC_LEN - 1) / (float)(RESOLUTION - 1));
        float fi  = floorf(src);
        int   i0  = (int)fi;
        int   i1  = min(i0 + 1, TC_LEN - 1);
        float w   = src - fi;
        curve[j]  = tc[i0] * (1.0f - w) + tc[i1] * w;
    }
    __syncthreads();

    const int q   = (blockIdx.x % FBPB) * 256 + threadIdx.x;
    const int off = q * 4;

    const float pivots[4] = {0.7f, 0.3f, 0.9f, 0.1f};
    const float invw[4]   = {1.0f / 0.1f, 1.0f / 0.12f, 1.0f / 0.08f, 1.0f / 0.08f};
    const float* sliders[4] = {S.highlights, S.shadows, S.whites, S.blacks};

    FrontP p = front_params(S, b);
    float strength[4], meanv[4];
    #pragma unroll
    for (int k = 0; k < 4; k++) {
        strength[k] = denorm(sliders[k][b], -100.f, 100.f) * 0.01f;
        meanv[k]    = partial_mean(ws_part, k, b);
    }
    float vib  = denorm(S.vibrance[b],   -100.f, 100.f) * 0.01f;
    float satg = 1.0f + denorm(S.saturation[b], -100.f, 100.f) * 0.01f;

    const float* base = image + (size_t)b * 3 * HW_PIX + off;
    float4 r4 = *reinterpret_cast<const float4*>(base);
    float4 g4 = *reinterpret_cast<const float4*>(base + HW_PIX);
    float4 b4 = *reinterpret_cast<const float4*>(base + 2 * HW_PIX);
    float* rr = reinterpret_cast<float*>(&r4);
    float* gg = reinterpret_cast<float*>(&g4);
    float* bb = reinterpret_cast<float*>(&b4);

    #pragma unroll
    for (int i = 0; i < 4; i++) {
        float r  = front_chan(rr[i], p.sr, p.em, p.cf);
        float g  = front_chan(gg[i], p.sg, p.em, p.cf);
        float bl = front_chan(bb[i], p.sb, p.em, p.cf);
        float lum = clampf(luminance(r, g, bl), 0.f, 1.f);

        // 4 sequential regions
        #pragma unroll
        for (int k = 0; k < 4; k++) {
            float mask = sigmoidf((lum - pivots[k]) * invw[k]);
            float nl   = clampf(lum + strength[k] * (mask - meanv[k]), 0.f, 1.f);
            float ratio = (lum > 1e-4f) ? nl / fmaxf(lum, 1e-4f) : 1.0f;
            r  = clampf(r * ratio, 0.f, 1.f);
            g  = clampf(g * ratio, 0.f, 1.f);
            bl = clampf(bl * ratio, 0.f, 1.f);
            lum = nl;
        }

        // tone curve (luma recomputed from img per reference)
        float tl = clampf(luminance(r, g, bl), 0.f, 1.f);
        float coords = tl * (float)(RESOLUTION - 1);
        float fidx = floorf(coords);
        int   i0 = (int)fidx;
        int   i1 = min(i0 + 1, RESOLUTION - 1);
        float w  = coords - fidx;
        float target = (1.0f - w) * curve[i0] + w * curve[i1];
        float ratio  = (tl > 1e-5f) ? target / fmaxf(tl, 1e-5f) : 1.0f;
        r  = clampf(r * ratio, 0.f, 1.f);
        g  = clampf(g * ratio, 0.f, 1.f);
        bl = clampf(bl * ratio, 0.f, 1.f);

        // vibrance
        float l2 = luminance(r, g, bl);
        float cr = r - l2, cg = g - l2, cb = bl - l2;
        float cn = sqrtf(cr * cr + cg * cg + cb * cb + 1e-6f);
        float gmask = __expf(-4.0f * cn);
        float vg = clampf(1.0f + vib * gmask, 0.2f, 4.0f);
        r  = clampf(l2 + cr * vg, 0.f, 1.f);
        g  = clampf(l2 + cg * vg, 0.f, 1.f);
        bl = clampf(l2 + cb * vg, 0.f, 1.f);

        // saturation (final clip(0,1) is identical to the saturation clip)
        float l3 = luminance(r, g, bl);
        r  = clampf(l3 + (r - l3) * satg, 0.f, 1.f);
        g  = clampf(l3 + (g - l3) * satg, 0.f, 1.f);
        bl = clampf(l3 + (bl - l3) * satg, 0.f, 1.f);

        rr[i] = r; gg[i] = g; bb[i] = bl;
    }

    float* obase = out + (size_t)b * 3 * HW_PIX + off;
    *reinterpret_cast<float4*>(obase)              = r4;
    *reinterpret_cast<float4*>(obase + HW_PIX)     = g4;
    *reinterpret_cast<float4*>(obase + 2 * HW_PIX) = b4;
}

extern "C" void kernel_launch(void* const* d_in, const int* in_sizes, int n_in,
                              void* d_out, int out_size, void* d_ws, size_t ws_size,
                              hipStream_t stream) {
    const float* image      = (const float*)d_in[0];
    const float* tone_curve = (const float*)d_in[1];
    Sliders S;
    S.temperature = (const float*)d_in[2];
    S.tint        = (const float*)d_in[3];
    S.exposure    = (const float*)d_in[4];
    S.contrast    = (const float*)d_in[5];
    S.highlights  = (const float*)d_in[6];
    S.shadows     = (const float*)d_in[7];
    S.whites      = (const float*)d_in[8];
    S.blacks      = (const float*)d_in[9];
    S.vibrance    = (const float*)d_in[10];
    S.saturation  = (const float*)d_in[11];
    float* out = (float*)d_out;

    // ws layout: [4][NBATCH][BPB] partials (24 KB), then 50 MB luma cache.
    float* ws_part = (float*)d_ws;
    float* ws_luma = (float*)d_ws + 4 * NBATCH * BPB + 64;
    bool use_luma = ws_size >= (4 * NBATCH * BPB + 64 + (size_t)NBATCH * HW_PIX) * sizeof(float);

    dim3 rgrid(NBATCH * BPB), block(256);
    if (use_luma) {
        reduce_kernel<0, true><<<rgrid, block, 0, stream>>>(image, S, ws_luma, ws_part);
        reduce_kernel<1, true><<<rgrid, block, 0, stream>>>(image, S, ws_luma, ws_part);
        reduce_kernel<2, true><<<rgrid, block, 0, stream>>>(image, S, ws_luma, ws_part);
        reduce_kernel<3, true><<<rgrid, block, 0, stream>>>(image, S, ws_luma, ws_part);
    } else {
        reduce_kernel<0, false><<<rgrid, block, 0, stream>>>(image, S, ws_luma, ws_part);
        reduce_kernel<1, false><<<rgrid, block, 0, stream>>>(image, S, ws_luma, ws_part);
        reduce_kernel<2, false><<<rgrid, block, 0, stream>>>(image, S, ws_luma, ws_part);
        reduce_kernel<3, false><<<rgrid, block, 0, stream>>>(image, S, ws_luma, ws_part);
    }
    dim3 fgrid(NBATCH * FBPB);
    final_kernel<<<fgrid, block, 0, stream>>>(image, tone_curve, S, ws_part, out);
}

// Round 3
// 432.489 us; speedup vs baseline: 1.8535x; 1.0671x over previous
//
#include <hip/hip_runtime.h>
#include <math.h>

#define H_DIM 1024
#define W_DIM 1536
#define HW_PIX (H_DIM * W_DIM)          // 1572864 pixels per (batch,channel)
#define NBATCH 8
#define QPB (HW_PIX / 4)                // quads per batch = 393216
#define BPB 192                          // reduce blocks per batch
#define QPT (QPB / (BPB * 256))          // quads per thread in reduce = 8
#define FBPB (QPB / 256)                 // final blocks per batch = 1536
#define RESOLUTION 1024
#define TC_LEN 256

struct Sliders {
    const float* temperature; const float* tint; const float* exposure; const float* contrast;
    const float* highlights;  const float* shadows; const float* whites; const float* blacks;
    const float* vibrance;    const float* saturation;
};

__device__ __forceinline__ float denorm(float v, float lo, float hi) {
    return lo + 0.5f * (v + 1.0f) * (hi - lo);
}
__device__ __forceinline__ float clamp01(float x) {
    return __builtin_amdgcn_fmed3f(x, 0.f, 1.f);
}
__device__ __forceinline__ float clampf(float x, float lo, float hi) {
    return fminf(fmaxf(x, lo), hi);
}
// sigmoid via hw exp2 + hw rcp (~4 ops vs ~14 for __expf + IEEE div)
__device__ __forceinline__ float sigmoidf(float x) {
    float t = __builtin_amdgcn_exp2f(x * -1.4426950408889634f);
    return __builtin_amdgcn_rcpf(1.0f + t);
}

struct FrontP { float sr, sg, sb, em, cf; };

__device__ __forceinline__ FrontP front_params(const Sliders& S, int b) {
    float temp = clampf(denorm(S.temperature[b], 2000.f, 50000.f), 2000.f, 50000.f);
    float tr   = 6500.f / temp;
    float red  = sqrtf(tr);
    float blue = 1.0f / sqrtf(tr);
    float ts   = clampf(denorm(S.tint[b], -150.f, 150.f) * (1.0f / 150.0f), -1.5f, 1.5f);
    float green = 1.0f - 0.1f * ts;
    red  *= (1.0f + 0.05f * ts);
    blue *= (1.0f - 0.05f * ts);
    float norm = fmaxf(fmaxf(red, green), blue);
    float inv  = 1.0f / fmaxf(norm, 1e-4f);
    FrontP p;
    p.sr = red * inv; p.sg = green * inv; p.sb = blue * inv;
    p.em = exp2f(denorm(S.exposure[b], -5.f, 5.f));
    p.cf = 1.0f + denorm(S.contrast[b], -100.f, 100.f) * 0.01f;
    return p;
}

// clip01 -> *gain (<=1 so clip(.,0,4) is a no-op) -> *em, clip upper 4 (>=0 free)
// -> contrast, clip01.
__device__ __forceinline__ float front_chan(float x, float s, float em, float cf) {
    x = clamp01(x);
    x = x * s;
    x = fminf(x * em, 4.0f);
    return clamp01((x - 0.5f) * cf + 0.5f);
}

__device__ __forceinline__ float luminance(float r, float g, float b) {
    return 0.2126f * r + 0.7152f * g + 0.0722f * b;
}

// Block (256 threads = 4 waves) double sum; result valid on thread 0 only.
__device__ __forceinline__ double block_sum_d(double v) {
    #pragma unroll
    for (int o = 32; o > 0; o >>= 1) v += __shfl_down(v, o, 64);
    __shared__ double s[4];
    int lane = threadIdx.x & 63, wid = threadIdx.x >> 6;
    if (lane == 0) s[wid] = v;
    __syncthreads();
    double r = 0.0;
    if (threadIdx.x == 0) r = s[0] + s[1] + s[2] + s[3];
    return r;
}

// Sum previous kernel's per-block double partials (block-uniform loads).
__device__ __forceinline__ float partial_mean(const double* __restrict__ ws_part, int k, int b) {
    const double* pp = ws_part + (k * NBATCH + b) * BPB;
    double s = 0.0;
    for (int j = 0; j < BPB; j++) s += pp[j];
    return (float)(s * (1.0 / (double)HW_PIX));
}

// R = region whose sigmoid-sum we reduce (0..3). Regions 0..R-1 replayed elementwise
// on luma using means from earlier kernels' partials. Each block writes its partial
// to a unique slot (no atomics).
template <int R, bool USE_LUMA>
__global__ __launch_bounds__(256)
void reduce_kernel(const float* __restrict__ image, Sliders S,
                   float* __restrict__ ws_luma, double* __restrict__ ws_part) {
    const int b   = blockIdx.x / BPB;
    const int blk = blockIdx.x % BPB;

    const float pivots[4] = {0.7f, 0.3f, 0.9f, 0.1f};
    const float invw[4]   = {1.0f / 0.1f, 1.0f / 0.12f, 1.0f / 0.08f, 1.0f / 0.08f};
    const float* sliders[4] = {S.highlights, S.shadows, S.whites, S.blacks};

    float strength[4], meanv[4];
    #pragma unroll
    for (int k = 0; k < R; k++) {
        strength[k] = denorm(sliders[k][b], -100.f, 100.f) * 0.01f;
        meanv[k]    = partial_mean(ws_part, k, b);
    }
    FrontP p = front_params(S, b);

    double sum = 0.0;
    #pragma unroll
    for (int it = 0; it < QPT; it++) {
        const int q   = blk * (256 * QPT) + it * 256 + threadIdx.x;
        const int off = q * 4;

        float4 L;
        if (USE_LUMA && R > 0) {
            L = *reinterpret_cast<const float4*>(ws_luma + (size_t)b * HW_PIX + off);
        } else {
            const float* base = image + (size_t)b * 3 * HW_PIX + off;
            float4 r4 = *reinterpret_cast<const float4*>(base);
            float4 g4 = *reinterpret_cast<const float4*>(base + HW_PIX);
            float4 b4 = *reinterpret_cast<const float4*>(base + 2 * HW_PIX);
            float* rr = reinterpret_cast<float*>(&r4);
            float* gg = reinterpret_cast<float*>(&g4);
            float* bb = reinterpret_cast<float*>(&b4);
            float* ll = reinterpret_cast<float*>(&L);
            #pragma unroll
            for (int i = 0; i < 4; i++) {
                float r  = front_chan(rr[i], p.sr, p.em, p.cf);
                float g  = front_chan(gg[i], p.sg, p.em, p.cf);
                float bl = front_chan(bb[i], p.sb, p.em, p.cf);
                ll[i] = clamp01(luminance(r, g, bl));
            }
            if (USE_LUMA && R == 0)
                *reinterpret_cast<float4*>(ws_luma + (size_t)b * HW_PIX + off) = L;
        }

        const float* ll = reinterpret_cast<const float*>(&L);
        #pragma unroll
        for (int i = 0; i < 4; i++) {
            float lum = ll[i];
            #pragma unroll
            for (int k = 0; k < R; k++) {
                float mask = sigmoidf((lum - pivots[k]) * invw[k]);
                lum = clamp01(lum + strength[k] * (mask - meanv[k]));
            }
            sum += (double)sigmoidf((lum - pivots[R]) * invw[R]);
        }
    }
    sum = block_sum_d(sum);
    if (threadIdx.x == 0) ws_part[(R * NBATCH + b) * BPB + blk] = sum;
}

__global__ __launch_bounds__(256)
void final_kernel(const float* __restrict__ image, const float* __restrict__ tone_curve,
                  Sliders S, const double* __restrict__ ws_part, float* __restrict__ out) {
    const int b = blockIdx.x / FBPB;

    // Build this batch's RESOLUTION-entry curve in LDS (replicates the reference's
    // align_corners interp of 256 control points -> 1024 samples).
    __shared__ float curve[RESOLUTION];
    const float* tc = tone_curve + b * TC_LEN;
    for (int j = threadIdx.x; j < RESOLUTION; j += 256) {
        float src = (float)j * ((float)(TC_LEN - 1) / (float)(RESOLUTION - 1));
        float fi  = floorf(src);
        int   i0  = (int)fi;
        int   i1  = min(i0 + 1, TC_LEN - 1);
        float w   = src - fi;
        curve[j]  = tc[i0] * (1.0f - w) + tc[i1] * w;
    }
    __syncthreads();

    const int q   = (blockIdx.x % FBPB) * 256 + threadIdx.x;
    const int off = q * 4;

    const float pivots[4] = {0.7f, 0.3f, 0.9f, 0.1f};
    const float invw[4]   = {1.0f / 0.1f, 1.0f / 0.12f, 1.0f / 0.08f, 1.0f / 0.08f};
    const float* sliders[4] = {S.highlights, S.shadows, S.whites, S.blacks};

    FrontP p = front_params(S, b);
    float strength[4], meanv[4];
    #pragma unroll
    for (int k = 0; k < 4; k++) {
        strength[k] = denorm(sliders[k][b], -100.f, 100.f) * 0.01f;
        meanv[k]    = partial_mean(ws_part, k, b);
    }
    float vib  = denorm(S.vibrance[b],   -100.f, 100.f) * 0.01f;
    float satg = 1.0f + denorm(S.saturation[b], -100.f, 100.f) * 0.01f;

    const float* base = image + (size_t)b * 3 * HW_PIX + off;
    float4 r4 = *reinterpret_cast<const float4*>(base);
    float4 g4 = *reinterpret_cast<const float4*>(base + HW_PIX);
    float4 b4 = *reinterpret_cast<const float4*>(base + 2 * HW_PIX);
    float* rr = reinterpret_cast<float*>(&r4);
    float* gg = reinterpret_cast<float*>(&g4);
    float* bb = reinterpret_cast<float*>(&b4);

    #pragma unroll
    for (int i = 0; i < 4; i++) {
        float r  = front_chan(rr[i], p.sr, p.em, p.cf);
        float g  = front_chan(gg[i], p.sg, p.em, p.cf);
        float bl = front_chan(bb[i], p.sb, p.em, p.cf);
        float lum = clamp01(luminance(r, g, bl));

        // 4 sequential regions. ratio>=0 so only the upper clamp is live on channels.
        #pragma unroll
        for (int k = 0; k < 4; k++) {
            float mask = sigmoidf((lum - pivots[k]) * invw[k]);
            float nl   = clamp01(lum + strength[k] * (mask - meanv[k]));
            float ratio = (lum > 1e-4f) ? nl * __builtin_amdgcn_rcpf(lum) : 1.0f;
            r  = fminf(r * ratio, 1.f);
            g  = fminf(g * ratio, 1.f);
            bl = fminf(bl * ratio, 1.f);
            lum = nl;
        }

        // tone curve (luma recomputed from img per reference); target>=0 -> fminf only
        float tl = clamp01(luminance(r, g, bl));
        float coords = tl * (float)(RESOLUTION - 1);
        float fidx = floorf(coords);
        int   i0 = (int)fidx;
        int   i1 = min(i0 + 1, RESOLUTION - 1);
        float w  = coords - fidx;
        float target = (1.0f - w) * curve[i0] + w * curve[i1];
        float ratio  = (tl > 1e-5f) ? target * __builtin_amdgcn_rcpf(tl) : 1.0f;
        r  = fminf(r * ratio, 1.f);
        g  = fminf(g * ratio, 1.f);
        bl = fminf(bl * ratio, 1.f);

        // vibrance
        float l2 = luminance(r, g, bl);
        float cr = r - l2, cg = g - l2, cb = bl - l2;
        float cn = sqrtf(cr * cr + cg * cg + cb * cb + 1e-6f);
        float gmask = __builtin_amdgcn_exp2f(cn * -5.771f); // exp(-4cn)
        float vg = __builtin_amdgcn_fmed3f(1.0f + vib * gmask, 0.2f, 4.0f);
        r  = clamp01(l2 + cr * vg);
        g  = clamp01(l2 + cg * vg);
        bl = clamp01(l2 + cb * vg);

        // saturation (final clip(0,1) is identical to the saturation clip)
        float l3 = luminance(r, g, bl);
        r  = clamp01(l3 + (r - l3) * satg);
        g  = clamp01(l3 + (g - l3) * satg);
        bl = clamp01(l3 + (bl - l3) * satg);

        rr[i] = r; gg[i] = g; bb[i] = bl;
    }

    float* obase = out + (size_t)b * 3 * HW_PIX + off;
    *reinterpret_cast<float4*>(obase)              = r4;
    *reinterpret_cast<float4*>(obase + HW_PIX)     = g4;
    *reinterpret_cast<float4*>(obase + 2 * HW_PIX) = b4;
}

extern "C" void kernel_launch(void* const* d_in, const int* in_sizes, int n_in,
                              void* d_out, int out_size, void* d_ws, size_t ws_size,
                              hipStream_t stream) {
    const float* image      = (const float*)d_in[0];
    const float* tone_curve = (const float*)d_in[1];
    Sliders S;
    S.temperature = (const float*)d_in[2];
    S.tint        = (const float*)d_in[3];
    S.exposure    = (const float*)d_in[4];
    S.contrast    = (const float*)d_in[5];
    S.highlights  = (const float*)d_in[6];
    S.shadows     = (const float*)d_in[7];
    S.whites      = (const float*)d_in[8];
    S.blacks      = (const float*)d_in[9];
    S.vibrance    = (const float*)d_in[10];
    S.saturation  = (const float*)d_in[11];
    float* out = (float*)d_out;

    // ws layout: double[4][NBATCH][BPB] partials (48 KB), then 50 MB luma cache.
    double* ws_part = (double*)d_ws;
    float*  ws_luma = (float*)((char*)d_ws + 4 * NBATCH * BPB * sizeof(double) + 256);
    bool use_luma = ws_size >= 4 * NBATCH * BPB * sizeof(double) + 256
                              + (size_t)NBATCH * HW_PIX * sizeof(float);

    dim3 rgrid(NBATCH * BPB), block(256);
    if (use_luma) {
        reduce_kernel<0, true><<<rgrid, block, 0, stream>>>(image, S, ws_luma, ws_part);
        reduce_kernel<1, true><<<rgrid, block, 0, stream>>>(image, S, ws_luma, ws_part);
        reduce_kernel<2, true><<<rgrid, block, 0, stream>>>(image, S, ws_luma, ws_part);
        reduce_kernel<3, true><<<rgrid, block, 0, stream>>>(image, S, ws_luma, ws_part);
    } else {
        reduce_kernel<0, false><<<rgrid, block, 0, stream>>>(image, S, ws_luma, ws_part);
        reduce_kernel<1, false><<<rgrid, block, 0, stream>>>(image, S, ws_luma, ws_part);
        reduce_kernel<2, false><<<rgrid, block, 0, stream>>>(image, S, ws_luma, ws_part);
        reduce_kernel<3, false><<<rgrid, block, 0, stream>>>(image, S, ws_luma, ws_part);
    }
    dim3 fgrid(NBATCH * FBPB);
    final_kernel<<<fgrid, block, 0, stream>>>(image, tone_curve, S, ws_part, out);
}